// Round 2
// baseline (7127.761 us; speedup 1.0000x reference)
//
#include <hip/hip_runtime.h>
#include <hip/hip_bf16.h>

// Problem constants (from reference): T=8192 steps, batch=1, H=21 hidden.
#define T_LEN 8192
#define HDIM  21
#define GDIM  84   // 4*H gate rows

// Workspace layout (floats):
//  zx1[T*84] zx2[T*84] zx3[T*84] h1[T*21] h2[T*21] h3[T*21] M1[84*21] M2[84*21] b3p[84]
//  total ~10.3 MB — assumed <= ws_size.
// NOTE: the scan prefetches up to 2 steps (2*84 floats) past the end of its zx
// buffer; each zx is followed by more mapped ws, so the overrun is safe and the
// values are never consumed in a way that affects output.

__device__ __forceinline__ float sigm(float x) {
    // stable: x->-inf: exp(+inf)=inf -> 0 ; x->+inf: exp(-inf)=0 -> 1
    return 1.0f / (1.0f + __expf(-x));
}
__device__ __forceinline__ float tanh_stable(float x) {
    // 1 - 2/(exp(2x)+1): x->+inf: e=inf -> 1 ; x->-inf: e=0 -> -1  (no inf/inf)
    float e = __expf(2.0f * x);
    return 1.0f - 2.0f / (e + 1.0f);
}

// ---------------------------------------------------------------------------
// K1: parallel input projections for LSTM1 and LSTM2.
// ---------------------------------------------------------------------------
__global__ void zx12_kernel(const float* __restrict__ src,
                            const float* __restrict__ Wih1, const float* __restrict__ b1,
                            const float* __restrict__ Wih2, const float* __restrict__ b2,
                            float* __restrict__ zx1, float* __restrict__ zx2)
{
    int g = blockIdx.x * blockDim.x + threadIdx.x;
    if (g >= T_LEN * GDIM) return;
    int t = g / GDIM, j = g - t * GDIM;
    float s0 = src[t * 4 + 0];
    float s1 = src[t * 4 + 1];
    float s2 = src[t * 4 + 2];
    float s3 = src[t * 4 + 3];
    float z1 = b1[j];
    z1 = __builtin_fmaf(Wih1[j * 3 + 0], s0, z1);
    z1 = __builtin_fmaf(Wih1[j * 3 + 1], s2, z1);
    z1 = __builtin_fmaf(Wih1[j * 3 + 2], s3, z1);
    float z2 = b2[j];
    z2 = __builtin_fmaf(Wih2[j * 3 + 0], s1, z2);
    z2 = __builtin_fmaf(Wih2[j * 3 + 1], s2, z2);
    z2 = __builtin_fmaf(Wih2[j * 3 + 2], s3, z2);
    zx1[g] = z1;
    zx2[g] = z2;
}

// ---------------------------------------------------------------------------
// K2: fold linear layers into LSTM3's input projection.
// ---------------------------------------------------------------------------
__global__ void fold_kernel(const float* __restrict__ Wih3,
                            const float* __restrict__ W1, const float* __restrict__ bl1,
                            const float* __restrict__ W2, const float* __restrict__ bl2,
                            const float* __restrict__ b3,
                            float* __restrict__ M1, float* __restrict__ M2,
                            float* __restrict__ b3p)
{
    int idx = blockIdx.x * blockDim.x + threadIdx.x;
    if (idx < GDIM * HDIM) {
        int j = idx / HDIM, k = idx - j * HDIM;
        M1[idx] = Wih3[j * 50 + 0] * W1[k];
        float s = 0.0f;
        for (int m = 0; m < 49; ++m)
            s = __builtin_fmaf(Wih3[j * 50 + 1 + m], W2[m * HDIM + k], s);
        M2[idx] = s;
    }
    if (idx < GDIM) {
        float s = b3[idx] + Wih3[idx * 50 + 0] * bl1[0];
        for (int m = 0; m < 49; ++m)
            s = __builtin_fmaf(Wih3[idx * 50 + 1 + m], bl2[m], s);
        b3p[idx] = s;
    }
}

// ---------------------------------------------------------------------------
// K3/K5: the sequential LSTM scan. ONE wave per block, zero barriers.
//   lane k   (k<21):  rowA = k      (i, sigmoid)   rowB = 42+k (g, tanh)
//   lane 32+k(k<21):  rowA = 21+k   (f, sigmoid)   rowB = 63+k (o, sigmoid)
// __launch_bounds__(64, 1): min 1 wave/EU -> full VGPR budget, NO SPILLS.
// Dot products split into 3x7 partial chains to cut dependent-FMA latency.
// ---------------------------------------------------------------------------
__global__ __launch_bounds__(64, 1)
void lstm_scan_kernel(const float* __restrict__ zxA, const float* __restrict__ WhhA,
                      float* __restrict__ houtA,
                      const float* __restrict__ zxB, const float* __restrict__ WhhB,
                      float* __restrict__ houtB)
{
    const float* zx   = (blockIdx.x == 0) ? zxA  : zxB;
    const float* Whh  = (blockIdx.x == 0) ? WhhA : WhhB;
    float*       hout = (blockIdx.x == 0) ? houtA : houtB;

    const int lane = threadIdx.x;
    const int k = lane & 31;
    const bool hi = lane >= 32;
    const bool act = k < HDIM;
    const int kk = act ? k : 0;

    const int rowA = hi ? (HDIM + kk)       : kk;              // f : i  (sigmoid)
    const int rowB = hi ? (3 * HDIM + kk)   : (2 * HDIM + kk); // o : g
    // vB activation: lo -> tanh via 2*sigm(2x)-1 ; hi -> sigm(x)
    const float sB = hi ? 1.0f : 2.0f;
    const float mB = hi ? 1.0f : 2.0f;
    const float aB = hi ? 0.0f : -1.0f;

    float wa[HDIM], wb[HDIM];
#pragma unroll
    for (int j = 0; j < HDIM; ++j) {
        wa[j] = Whh[rowA * HDIM + j];
        wb[j] = Whh[rowB * HDIM + j];
    }

    float hs[HDIM];
#pragma unroll
    for (int j = 0; j < HDIM; ++j) hs[j] = 0.0f;
    float c = 0.0f;

    // software-pipelined zx prefetch, depth 2 (reads 2 steps past end: mapped ws)
    float za  = zx[rowA],        zb  = zx[rowB];
    float zaN = zx[GDIM + rowA], zbN = zx[GDIM + rowB];

    for (int t = 0; t < T_LEN; ++t) {
        float za2 = zx[(t + 2) * GDIM + rowA];
        float zb2 = zx[(t + 2) * GDIM + rowB];

        // 21-term dots as 3 partial chains of 7 (latency ~40cy instead of ~84)
        float a0 = za,  a1 = 0.0f, a2 = 0.0f;
        float b0 = zb,  b1 = 0.0f, b2 = 0.0f;
#pragma unroll
        for (int j = 0; j < 7; ++j) {
            a0 = __builtin_fmaf(wa[j],      hs[j],      a0);
            b0 = __builtin_fmaf(wb[j],      hs[j],      b0);
            a1 = __builtin_fmaf(wa[j + 7],  hs[j + 7],  a1);
            b1 = __builtin_fmaf(wb[j + 7],  hs[j + 7],  b1);
            a2 = __builtin_fmaf(wa[j + 14], hs[j + 14], a2);
            b2 = __builtin_fmaf(wb[j + 14], hs[j + 14], b2);
        }
        float accA = (a0 + a1) + a2;
        float accB = (b0 + b1) + b2;

        float vA = sigm(accA);                                   // sig(i) | sig(f)
        float vB = __builtin_fmaf(mB, sigm(sB * accB), aB);      // tanh(g) | sig(o)

        float p   = vA * vB;               // lo: sig(i)*tanh(g)
        float pSw = __shfl_xor(p, 32);     // hi lanes receive lo's p

        c = __builtin_fmaf(vA, c, pSw);    // hi: sig(f)*c + sig(i)*tanh(g)
        float th = tanh_stable(c);
        float h  = vB * th;                // hi: sig(o)*tanh(c)

        if (hi && act) hout[t * HDIM + k] = h;

        // broadcast new h (lanes 32..52) to wave-uniform scalars (SGPRs)
#pragma unroll
        for (int j = 0; j < HDIM; ++j) {
            hs[j] = __int_as_float(
                __builtin_amdgcn_readlane(__float_as_int(h), 32 + j));
        }

        za = zaN; zb = zbN; zaN = za2; zbN = zb2;
    }
}

// ---------------------------------------------------------------------------
// K4: parallel zx3 from stored h1,h2 and folded M1,M2.
// ---------------------------------------------------------------------------
__global__ void zx3_kernel(const float* __restrict__ h1, const float* __restrict__ h2,
                           const float* __restrict__ M1, const float* __restrict__ M2,
                           const float* __restrict__ b3p, float* __restrict__ zx3)
{
    int g = blockIdx.x * blockDim.x + threadIdx.x;
    if (g >= T_LEN * GDIM) return;
    int t = g / GDIM, j = g - t * GDIM;
    const float* h1t = h1 + t * HDIM;
    const float* h2t = h2 + t * HDIM;
    const float* m1  = M1 + j * HDIM;
    const float* m2  = M2 + j * HDIM;
    float s = b3p[j];
#pragma unroll
    for (int kq = 0; kq < HDIM; ++kq) {
        s = __builtin_fmaf(m1[kq], h1t[kq], s);
        s = __builtin_fmaf(m2[kq], h2t[kq], s);
    }
    zx3[g] = s;
}

// ---------------------------------------------------------------------------
// K6: final linear: out[t] = h3[t] @ W3.T + bl3   (W3: [2,21])
// ---------------------------------------------------------------------------
__global__ void out_kernel(const float* __restrict__ h3, const float* __restrict__ W3,
                           const float* __restrict__ bl3, float* __restrict__ out)
{
    int t = blockIdx.x * blockDim.x + threadIdx.x;
    if (t >= T_LEN) return;
    float s0 = bl3[0], s1 = bl3[1];
#pragma unroll
    for (int kq = 0; kq < HDIM; ++kq) {
        float h = h3[t * HDIM + kq];
        s0 = __builtin_fmaf(W3[kq], h, s0);
        s1 = __builtin_fmaf(W3[HDIM + kq], h, s1);
    }
    out[t * 2 + 0] = s0;
    out[t * 2 + 1] = s1;
}

extern "C" void kernel_launch(void* const* d_in, const int* in_sizes, int n_in,
                              void* d_out, int out_size, void* d_ws, size_t ws_size,
                              hipStream_t stream) {
    const float* src  = (const float*)d_in[0];
    const float* Wih1 = (const float*)d_in[1];
    const float* Whh1 = (const float*)d_in[2];
    const float* b1   = (const float*)d_in[3];
    const float* W1   = (const float*)d_in[4];
    const float* bl1  = (const float*)d_in[5];
    const float* Wih2 = (const float*)d_in[6];
    const float* Whh2 = (const float*)d_in[7];
    const float* b2   = (const float*)d_in[8];
    const float* W2   = (const float*)d_in[9];
    const float* bl2  = (const float*)d_in[10];
    const float* Wih3 = (const float*)d_in[11];
    const float* Whh3 = (const float*)d_in[12];
    const float* b3   = (const float*)d_in[13];
    const float* W3   = (const float*)d_in[14];
    const float* bl3  = (const float*)d_in[15];
    float* out = (float*)d_out;

    float* ws  = (float*)d_ws;
    float* zx1 = ws;
    float* zx2 = zx1 + (size_t)T_LEN * GDIM;
    float* zx3 = zx2 + (size_t)T_LEN * GDIM;
    float* h1  = zx3 + (size_t)T_LEN * GDIM;
    float* h2  = h1  + (size_t)T_LEN * HDIM;
    float* h3  = h2  + (size_t)T_LEN * HDIM;
    float* M1  = h3  + (size_t)T_LEN * HDIM;
    float* M2  = M1  + GDIM * HDIM;
    float* b3p = M2  + GDIM * HDIM;

    zx12_kernel<<<(T_LEN * GDIM + 255) / 256, 256, 0, stream>>>(
        src, Wih1, b1, Wih2, b2, zx1, zx2);
    fold_kernel<<<(GDIM * HDIM + 255) / 256, 256, 0, stream>>>(
        Wih3, W1, bl1, W2, bl2, b3, M1, M2, b3p);
    lstm_scan_kernel<<<2, 64, 0, stream>>>(zx1, Whh1, h1, zx2, Whh2, h2);
    zx3_kernel<<<(T_LEN * GDIM + 255) / 256, 256, 0, stream>>>(
        h1, h2, M1, M2, b3p, zx3);
    lstm_scan_kernel<<<1, 64, 0, stream>>>(zx3, Whh3, h3, zx3, Whh3, h3);
    out_kernel<<<(T_LEN + 255) / 256, 256, 0, stream>>>(h3, W3, bl3, out);
}

// Round 5
// 4557.830 us; speedup vs baseline: 1.5638x; 1.5638x over previous
//
#include <hip/hip_runtime.h>
#include <hip/hip_bf16.h>

// Problem constants (from reference): T=8192 steps, batch=1, H=21 hidden.
#define T_LEN 8192
#define HDIM  21
#define GDIM  84   // 4*H gate rows

// Workspace layout (floats):
//  zxT1[84*8192] zxT2[84*8192] zxT3[84*8192]   (TRANSPOSED: [row][t])
//  h1[8192*21] h2[8192*21] h3[8192*21] M1[84*21] M2[84*21] b3p[84]
//  total ~10.3 MB <= ws_size.
// NOTE: the scan prefetches up to 8 floats past the end of each row's stream;
// worst case (last row of zxT3) reads 8 floats past the buffer into the
// following mapped ws region (h1). Values are never consumed.

__device__ __forceinline__ float sigm(float x) {
    return 1.0f / (1.0f + __expf(-x));   // stable both directions
}
__device__ __forceinline__ float tanh_stable(float x) {
    float e = __expf(2.0f * x);          // x->+inf: 1 ; x->-inf: -1 ; no inf/inf
    return 1.0f - 2.0f / (e + 1.0f);
}

// ---------------------------------------------------------------------------
// K1: parallel input projections, TRANSPOSED output zxT[j*8192 + t].
// ---------------------------------------------------------------------------
__global__ void zx12_kernel(const float* __restrict__ src,
                            const float* __restrict__ Wih1, const float* __restrict__ b1,
                            const float* __restrict__ Wih2, const float* __restrict__ b2,
                            float* __restrict__ zxT1, float* __restrict__ zxT2)
{
    int n = blockIdx.x * blockDim.x + threadIdx.x;
    if (n >= T_LEN * GDIM) return;
    int j = n >> 13;            // row (0..83)
    int t = n & (T_LEN - 1);    // time
    float4 s = *reinterpret_cast<const float4*>(src + 4 * t);
    float z1 = b1[j];
    z1 = __builtin_fmaf(Wih1[j * 3 + 0], s.x, z1);
    z1 = __builtin_fmaf(Wih1[j * 3 + 1], s.z, z1);
    z1 = __builtin_fmaf(Wih1[j * 3 + 2], s.w, z1);
    float z2 = b2[j];
    z2 = __builtin_fmaf(Wih2[j * 3 + 0], s.y, z2);
    z2 = __builtin_fmaf(Wih2[j * 3 + 1], s.z, z2);
    z2 = __builtin_fmaf(Wih2[j * 3 + 2], s.w, z2);
    zxT1[n] = z1;
    zxT2[n] = z2;
}

// ---------------------------------------------------------------------------
// K2: fold linear layers into LSTM3's input projection.
// ---------------------------------------------------------------------------
__global__ void fold_kernel(const float* __restrict__ Wih3,
                            const float* __restrict__ W1, const float* __restrict__ bl1,
                            const float* __restrict__ W2, const float* __restrict__ bl2,
                            const float* __restrict__ b3,
                            float* __restrict__ M1, float* __restrict__ M2,
                            float* __restrict__ b3p)
{
    int idx = blockIdx.x * blockDim.x + threadIdx.x;
    if (idx < GDIM * HDIM) {
        int j = idx / HDIM, k = idx - j * HDIM;
        M1[idx] = Wih3[j * 50 + 0] * W1[k];
        float s = 0.0f;
        for (int m = 0; m < 49; ++m)
            s = __builtin_fmaf(Wih3[j * 50 + 1 + m], W2[m * HDIM + k], s);
        M2[idx] = s;
    }
    if (idx < GDIM) {
        float s = b3[idx] + Wih3[idx * 50 + 0] * bl1[0];
        for (int m = 0; m < 49; ++m)
            s = __builtin_fmaf(Wih3[idx * 50 + 1 + m], bl2[m], s);
        b3p[idx] = s;
    }
}

// ---------------------------------------------------------------------------
// K3/K5: sequential LSTM scan. ONE wave, zero barriers, ZERO ARRAYS —
// every per-lane value is a named scalar so nothing can demote to scratch.
//   lane k   (k<21):  rowA = k    (i, sigmoid)   rowB = 42+k (g, tanh)
//   lane 32+k(k<21):  rowA = 21+k (f, sigmoid)   rowB = 63+k (o, sigmoid)
// zx is transposed [row][t]: each lane streams its 2 rows contiguously,
// one float4 per 4 steps, prefetched 8 steps ahead.
// ---------------------------------------------------------------------------
#define RL(h_, l_) __int_as_float(__builtin_amdgcn_readlane(__float_as_int(h_), 32 + (l_)))

#define BCAST_H(h_)                                                        \
    hs_0  = RL(h_, 0);  hs_1  = RL(h_, 1);  hs_2  = RL(h_, 2);             \
    hs_3  = RL(h_, 3);  hs_4  = RL(h_, 4);  hs_5  = RL(h_, 5);             \
    hs_6  = RL(h_, 6);  hs_7  = RL(h_, 7);  hs_8  = RL(h_, 8);             \
    hs_9  = RL(h_, 9);  hs_10 = RL(h_, 10); hs_11 = RL(h_, 11);            \
    hs_12 = RL(h_, 12); hs_13 = RL(h_, 13); hs_14 = RL(h_, 14);            \
    hs_15 = RL(h_, 15); hs_16 = RL(h_, 16); hs_17 = RL(h_, 17);            \
    hs_18 = RL(h_, 18); hs_19 = RL(h_, 19); hs_20 = RL(h_, 20);

#define STEP(zA_, zB_, tt_)                                                \
    {                                                                      \
        float a0 = (zA_), a1 = 0.0f, a2 = 0.0f;                            \
        float b0 = (zB_), b1 = 0.0f, b2 = 0.0f;                            \
        a0 = __builtin_fmaf(wa_0,  hs_0,  a0);                             \
        b0 = __builtin_fmaf(wb_0,  hs_0,  b0);                             \
        a0 = __builtin_fmaf(wa_1,  hs_1,  a0);                             \
        b0 = __builtin_fmaf(wb_1,  hs_1,  b0);                             \
        a0 = __builtin_fmaf(wa_2,  hs_2,  a0);                             \
        b0 = __builtin_fmaf(wb_2,  hs_2,  b0);                             \
        a0 = __builtin_fmaf(wa_3,  hs_3,  a0);                             \
        b0 = __builtin_fmaf(wb_3,  hs_3,  b0);                             \
        a0 = __builtin_fmaf(wa_4,  hs_4,  a0);                             \
        b0 = __builtin_fmaf(wb_4,  hs_4,  b0);                             \
        a0 = __builtin_fmaf(wa_5,  hs_5,  a0);                             \
        b0 = __builtin_fmaf(wb_5,  hs_5,  b0);                             \
        a0 = __builtin_fmaf(wa_6,  hs_6,  a0);                             \
        b0 = __builtin_fmaf(wb_6,  hs_6,  b0);                             \
        a1 = __builtin_fmaf(wa_7,  hs_7,  a1);                             \
        b1 = __builtin_fmaf(wb_7,  hs_7,  b1);                             \
        a1 = __builtin_fmaf(wa_8,  hs_8,  a1);                             \
        b1 = __builtin_fmaf(wb_8,  hs_8,  b1);                             \
        a1 = __builtin_fmaf(wa_9,  hs_9,  a1);                             \
        b1 = __builtin_fmaf(wb_9,  hs_9,  b1);                             \
        a1 = __builtin_fmaf(wa_10, hs_10, a1);                             \
        b1 = __builtin_fmaf(wb_10, hs_10, b1);                             \
        a1 = __builtin_fmaf(wa_11, hs_11, a1);                             \
        b1 = __builtin_fmaf(wb_11, hs_11, b1);                             \
        a1 = __builtin_fmaf(wa_12, hs_12, a1);                             \
        b1 = __builtin_fmaf(wb_12, hs_12, b1);                             \
        a1 = __builtin_fmaf(wa_13, hs_13, a1);                             \
        b1 = __builtin_fmaf(wb_13, hs_13, b1);                             \
        a2 = __builtin_fmaf(wa_14, hs_14, a2);                             \
        b2 = __builtin_fmaf(wb_14, hs_14, b2);                             \
        a2 = __builtin_fmaf(wa_15, hs_15, a2);                             \
        b2 = __builtin_fmaf(wb_15, hs_15, b2);                             \
        a2 = __builtin_fmaf(wa_16, hs_16, a2);                             \
        b2 = __builtin_fmaf(wb_16, hs_16, b2);                             \
        a2 = __builtin_fmaf(wa_17, hs_17, a2);                             \
        b2 = __builtin_fmaf(wb_17, hs_17, b2);                             \
        a2 = __builtin_fmaf(wa_18, hs_18, a2);                             \
        b2 = __builtin_fmaf(wb_18, hs_18, b2);                             \
        a2 = __builtin_fmaf(wa_19, hs_19, a2);                             \
        b2 = __builtin_fmaf(wb_19, hs_19, b2);                             \
        a2 = __builtin_fmaf(wa_20, hs_20, a2);                             \
        b2 = __builtin_fmaf(wb_20, hs_20, b2);                             \
        float accA = (a0 + a1) + a2;                                       \
        float accB = (b0 + b1) + b2;                                       \
        float vA = sigm(accA);                                             \
        float vB = __builtin_fmaf(mB, sigm(sB * accB), aB);                \
        float p   = vA * vB;                                               \
        float pSw = __shfl_xor(p, 32);                                     \
        c = __builtin_fmaf(vA, c, pSw);                                    \
        float th = tanh_stable(c);                                         \
        float h  = vB * th;                                                \
        if (hi && act) hout[(tt_) * HDIM + k] = h;                         \
        BCAST_H(h)                                                         \
    }

__global__ __launch_bounds__(64, 1)
void lstm_scan_kernel(const float* __restrict__ zxA, const float* __restrict__ WhhA,
                      float* __restrict__ houtA,
                      const float* __restrict__ zxB, const float* __restrict__ WhhB,
                      float* __restrict__ houtB)
{
    const float* zxT  = (blockIdx.x == 0) ? zxA  : zxB;
    const float* Whh  = (blockIdx.x == 0) ? WhhA : WhhB;
    float*       hout = (blockIdx.x == 0) ? houtA : houtB;

    const int lane = threadIdx.x;
    const int k = lane & 31;
    const bool hi = lane >= 32;
    const bool act = k < HDIM;
    const int kk = act ? k : 0;

    const int rowA = hi ? (HDIM + kk)     : kk;              // f : i  (sigmoid)
    const int rowB = hi ? (3 * HDIM + kk) : (2 * HDIM + kk); // o : g
    const float sB = hi ? 1.0f : 2.0f;   // vB: lo tanh via 2*sigm(2x)-1, hi sigm
    const float mB = hi ? 1.0f : 2.0f;
    const float aB = hi ? 0.0f : -1.0f;

    const float* pA = zxT + (size_t)rowA * T_LEN;
    const float* pB = zxT + (size_t)rowB * T_LEN;
    const float* WA = Whh + rowA * HDIM;
    const float* WB = Whh + rowB * HDIM;

    // weights: 42 NAMED scalars -> guaranteed VGPRs
    float wa_0  = WA[0],  wa_1  = WA[1],  wa_2  = WA[2],  wa_3  = WA[3];
    float wa_4  = WA[4],  wa_5  = WA[5],  wa_6  = WA[6],  wa_7  = WA[7];
    float wa_8  = WA[8],  wa_9  = WA[9],  wa_10 = WA[10], wa_11 = WA[11];
    float wa_12 = WA[12], wa_13 = WA[13], wa_14 = WA[14], wa_15 = WA[15];
    float wa_16 = WA[16], wa_17 = WA[17], wa_18 = WA[18], wa_19 = WA[19];
    float wa_20 = WA[20];
    float wb_0  = WB[0],  wb_1  = WB[1],  wb_2  = WB[2],  wb_3  = WB[3];
    float wb_4  = WB[4],  wb_5  = WB[5],  wb_6  = WB[6],  wb_7  = WB[7];
    float wb_8  = WB[8],  wb_9  = WB[9],  wb_10 = WB[10], wb_11 = WB[11];
    float wb_12 = WB[12], wb_13 = WB[13], wb_14 = WB[14], wb_15 = WB[15];
    float wb_16 = WB[16], wb_17 = WB[17], wb_18 = WB[18], wb_19 = WB[19];
    float wb_20 = WB[20];

    // h state: 21 named scalars (wave-uniform after readlane -> SGPRs)
    float hs_0 = 0, hs_1 = 0, hs_2 = 0, hs_3 = 0, hs_4 = 0, hs_5 = 0, hs_6 = 0;
    float hs_7 = 0, hs_8 = 0, hs_9 = 0, hs_10 = 0, hs_11 = 0, hs_12 = 0;
    float hs_13 = 0, hs_14 = 0, hs_15 = 0, hs_16 = 0, hs_17 = 0, hs_18 = 0;
    float hs_19 = 0, hs_20 = 0;
    float c = 0.0f;

    // zx stream: float4 per 4 steps per row, named regs, 8-step lookahead
    float4 cA = *reinterpret_cast<const float4*>(pA);
    float4 cB = *reinterpret_cast<const float4*>(pB);
    float4 nA = *reinterpret_cast<const float4*>(pA + 4);
    float4 nB = *reinterpret_cast<const float4*>(pB + 4);

    for (int t = 0; t < T_LEN; t += 4) {
        float4 fA = *reinterpret_cast<const float4*>(pA + t + 8); // overrun ok (mapped ws)
        float4 fB = *reinterpret_cast<const float4*>(pB + t + 8);
        STEP(cA.x, cB.x, t + 0)
        STEP(cA.y, cB.y, t + 1)
        STEP(cA.z, cB.z, t + 2)
        STEP(cA.w, cB.w, t + 3)
        cA = nA; cB = nB; nA = fA; nB = fB;
    }
}

// ---------------------------------------------------------------------------
// K4: parallel zx3 from h1,h2 and folded M1,M2; TRANSPOSED output.
// ---------------------------------------------------------------------------
__global__ void zx3_kernel(const float* __restrict__ h1, const float* __restrict__ h2,
                           const float* __restrict__ M1, const float* __restrict__ M2,
                           const float* __restrict__ b3p, float* __restrict__ zxT3)
{
    int n = blockIdx.x * blockDim.x + threadIdx.x;
    if (n >= T_LEN * GDIM) return;
    int j = n >> 13;
    int t = n & (T_LEN - 1);
    const float* h1t = h1 + t * HDIM;
    const float* h2t = h2 + t * HDIM;
    const float* m1  = M1 + j * HDIM;
    const float* m2  = M2 + j * HDIM;
    float s = b3p[j];
#pragma unroll
    for (int kq = 0; kq < HDIM; ++kq) {
        s = __builtin_fmaf(m1[kq], h1t[kq], s);
        s = __builtin_fmaf(m2[kq], h2t[kq], s);
    }
    zxT3[n] = s;
}

// ---------------------------------------------------------------------------
// K6: final linear: out[t] = h3[t] @ W3.T + bl3   (W3: [2,21])
// ---------------------------------------------------------------------------
__global__ void out_kernel(const float* __restrict__ h3, const float* __restrict__ W3,
                           const float* __restrict__ bl3, float* __restrict__ out)
{
    int t = blockIdx.x * blockDim.x + threadIdx.x;
    if (t >= T_LEN) return;
    float s0 = bl3[0], s1 = bl3[1];
#pragma unroll
    for (int kq = 0; kq < HDIM; ++kq) {
        float h = h3[t * HDIM + kq];
        s0 = __builtin_fmaf(W3[kq], h, s0);
        s1 = __builtin_fmaf(W3[HDIM + kq], h, s1);
    }
    out[t * 2 + 0] = s0;
    out[t * 2 + 1] = s1;
}

extern "C" void kernel_launch(void* const* d_in, const int* in_sizes, int n_in,
                              void* d_out, int out_size, void* d_ws, size_t ws_size,
                              hipStream_t stream) {
    const float* src  = (const float*)d_in[0];
    const float* Wih1 = (const float*)d_in[1];
    const float* Whh1 = (const float*)d_in[2];
    const float* b1   = (const float*)d_in[3];
    const float* W1   = (const float*)d_in[4];
    const float* bl1  = (const float*)d_in[5];
    const float* Wih2 = (const float*)d_in[6];
    const float* Whh2 = (const float*)d_in[7];
    const float* b2   = (const float*)d_in[8];
    const float* W2   = (const float*)d_in[9];
    const float* bl2  = (const float*)d_in[10];
    const float* Wih3 = (const float*)d_in[11];
    const float* Whh3 = (const float*)d_in[12];
    const float* b3   = (const float*)d_in[13];
    const float* W3   = (const float*)d_in[14];
    const float* bl3  = (const float*)d_in[15];
    float* out = (float*)d_out;

    float* ws   = (float*)d_ws;
    float* zxT1 = ws;
    float* zxT2 = zxT1 + (size_t)T_LEN * GDIM;
    float* zxT3 = zxT2 + (size_t)T_LEN * GDIM;
    float* h1   = zxT3 + (size_t)T_LEN * GDIM;
    float* h2   = h1   + (size_t)T_LEN * HDIM;
    float* h3   = h2   + (size_t)T_LEN * HDIM;
    float* M1   = h3   + (size_t)T_LEN * HDIM;
    float* M2   = M1   + GDIM * HDIM;
    float* b3p  = M2   + GDIM * HDIM;

    zx12_kernel<<<(T_LEN * GDIM + 255) / 256, 256, 0, stream>>>(
        src, Wih1, b1, Wih2, b2, zxT1, zxT2);
    fold_kernel<<<(GDIM * HDIM + 255) / 256, 256, 0, stream>>>(
        Wih3, W1, bl1, W2, bl2, b3, M1, M2, b3p);
    lstm_scan_kernel<<<2, 64, 0, stream>>>(zxT1, Whh1, h1, zxT2, Whh2, h2);
    zx3_kernel<<<(T_LEN * GDIM + 255) / 256, 256, 0, stream>>>(
        h1, h2, M1, M2, b3p, zxT3);
    lstm_scan_kernel<<<1, 64, 0, stream>>>(zxT3, Whh3, h3, zxT3, Whh3, h3);
    out_kernel<<<(T_LEN + 255) / 256, 256, 0, stream>>>(h3, W3, bl3, out);
}

// Round 9
// 4341.758 us; speedup vs baseline: 1.6417x; 1.0498x over previous
//
#include <hip/hip_runtime.h>
#include <hip/hip_bf16.h>

// Problem constants (from reference): T=8192 steps, batch=1, H=21 hidden.
#define T_LEN 8192
#define HDIM  21
#define GDIM  84          // 4*H gate rows
#define NGRP  (T_LEN / 4) // 2048 groups of 4 timesteps
#define GSTRIDE (GDIM * 4) // 336 floats per group block

// Workspace layout (floats):
//  zxG1[2048*336] zxG2[...] zxG3[...]   (GROUPED: [t/4][row][4])
//  h1[8192*21] h2[8192*21] h3[8192*21] M1[84*21] M2[84*21] b3p[84]
//  total ~10.3 MB <= ws_size.
// NOTE: the scan issues loads up to 8 groups (10.8 KB) past the end of its zx
// buffer; each zx buffer is followed by more mapped ws, so the overrun is safe
// and the values are never consumed.

__device__ __forceinline__ float sigm(float x) {
    return 1.0f / (1.0f + __expf(-x));   // stable both directions
}
__device__ __forceinline__ float tanh_stable(float x) {
    float e = __expf(2.0f * x);          // x->+inf: 1 ; x->-inf: -1 ; no inf/inf
    return 1.0f - 2.0f / (e + 1.0f);
}

// ---------------------------------------------------------------------------
// K1: parallel input projections, GROUPED output zxG[g][j][q], coalesced writes.
// n = g*336 + j*4 + q ; t = 4g+q
// ---------------------------------------------------------------------------
__global__ void zx12_kernel(const float* __restrict__ src,
                            const float* __restrict__ Wih1, const float* __restrict__ b1,
                            const float* __restrict__ Wih2, const float* __restrict__ b2,
                            float* __restrict__ zxG1, float* __restrict__ zxG2)
{
    int n = blockIdx.x * blockDim.x + threadIdx.x;
    if (n >= T_LEN * GDIM) return;
    unsigned g = (unsigned)n / GSTRIDE;
    unsigned r = (unsigned)n - g * GSTRIDE;
    unsigned j = r >> 2;
    unsigned t = (g << 2) | (r & 3);
    float4 s = *reinterpret_cast<const float4*>(src + 4 * t);
    float z1 = b1[j];
    z1 = __builtin_fmaf(Wih1[j * 3 + 0], s.x, z1);
    z1 = __builtin_fmaf(Wih1[j * 3 + 1], s.z, z1);
    z1 = __builtin_fmaf(Wih1[j * 3 + 2], s.w, z1);
    float z2 = b2[j];
    z2 = __builtin_fmaf(Wih2[j * 3 + 0], s.y, z2);
    z2 = __builtin_fmaf(Wih2[j * 3 + 1], s.z, z2);
    z2 = __builtin_fmaf(Wih2[j * 3 + 2], s.w, z2);
    zxG1[n] = z1;
    zxG2[n] = z2;
}

// ---------------------------------------------------------------------------
// K2: fold linear layers into LSTM3's input projection.
// ---------------------------------------------------------------------------
__global__ void fold_kernel(const float* __restrict__ Wih3,
                            const float* __restrict__ W1, const float* __restrict__ bl1,
                            const float* __restrict__ W2, const float* __restrict__ bl2,
                            const float* __restrict__ b3,
                            float* __restrict__ M1, float* __restrict__ M2,
                            float* __restrict__ b3p)
{
    int idx = blockIdx.x * blockDim.x + threadIdx.x;
    if (idx < GDIM * HDIM) {
        int j = idx / HDIM, k = idx - j * HDIM;
        M1[idx] = Wih3[j * 50 + 0] * W1[k];
        float s = 0.0f;
        for (int m = 0; m < 49; ++m)
            s = __builtin_fmaf(Wih3[j * 50 + 1 + m], W2[m * HDIM + k], s);
        M2[idx] = s;
    }
    if (idx < GDIM) {
        float s = b3[idx] + Wih3[idx * 50 + 0] * bl1[0];
        for (int m = 0; m < 49; ++m)
            s = __builtin_fmaf(Wih3[idx * 50 + 1 + m], bl2[m], s);
        b3p[idx] = s;
    }
}

// ---------------------------------------------------------------------------
// K3/K5: sequential LSTM scan. ONE wave, zero barriers, zero arrays.
//   lane k   (k<21):  rowA = k    (i, sigmoid)   rowB = 42+k (g, tanh)
//   lane 32+k(k<21):  rowA = 21+k (f, sigmoid)   rowB = 63+k (o, sigmoid)
// zx is GROUPED [g][row][4]: per group the wave reads one contiguous 1344B
// block (lane stride 16B -> coalesced). 3-bank pipeline: loads for group g+8
// are issued at group g and first waited on 16 steps later.
// ---------------------------------------------------------------------------
#define RL(h_, l_) __int_as_float(__builtin_amdgcn_readlane(__float_as_int(h_), 32 + (l_)))

#define BCAST_H(h_)                                                        \
    hs_0  = RL(h_, 0);  hs_1  = RL(h_, 1);  hs_2  = RL(h_, 2);             \
    hs_3  = RL(h_, 3);  hs_4  = RL(h_, 4);  hs_5  = RL(h_, 5);             \
    hs_6  = RL(h_, 6);  hs_7  = RL(h_, 7);  hs_8  = RL(h_, 8);             \
    hs_9  = RL(h_, 9);  hs_10 = RL(h_, 10); hs_11 = RL(h_, 11);            \
    hs_12 = RL(h_, 12); hs_13 = RL(h_, 13); hs_14 = RL(h_, 14);            \
    hs_15 = RL(h_, 15); hs_16 = RL(h_, 16); hs_17 = RL(h_, 17);            \
    hs_18 = RL(h_, 18); hs_19 = RL(h_, 19); hs_20 = RL(h_, 20);

#define STEP(zA_, zB_, tt_)                                                \
    {                                                                      \
        float a0 = (zA_), a1 = 0.0f, a2 = 0.0f;                            \
        float b0 = (zB_), b1 = 0.0f, b2 = 0.0f;                            \
        a0 = __builtin_fmaf(wa_0,  hs_0,  a0);                             \
        b0 = __builtin_fmaf(wb_0,  hs_0,  b0);                             \
        a0 = __builtin_fmaf(wa_1,  hs_1,  a0);                             \
        b0 = __builtin_fmaf(wb_1,  hs_1,  b0);                             \
        a0 = __builtin_fmaf(wa_2,  hs_2,  a0);                             \
        b0 = __builtin_fmaf(wb_2,  hs_2,  b0);                             \
        a0 = __builtin_fmaf(wa_3,  hs_3,  a0);                             \
        b0 = __builtin_fmaf(wb_3,  hs_3,  b0);                             \
        a0 = __builtin_fmaf(wa_4,  hs_4,  a0);                             \
        b0 = __builtin_fmaf(wb_4,  hs_4,  b0);                             \
        a0 = __builtin_fmaf(wa_5,  hs_5,  a0);                             \
        b0 = __builtin_fmaf(wb_5,  hs_5,  b0);                             \
        a0 = __builtin_fmaf(wa_6,  hs_6,  a0);                             \
        b0 = __builtin_fmaf(wb_6,  hs_6,  b0);                             \
        a1 = __builtin_fmaf(wa_7,  hs_7,  a1);                             \
        b1 = __builtin_fmaf(wb_7,  hs_7,  b1);                             \
        a1 = __builtin_fmaf(wa_8,  hs_8,  a1);                             \
        b1 = __builtin_fmaf(wb_8,  hs_8,  b1);                             \
        a1 = __builtin_fmaf(wa_9,  hs_9,  a1);                             \
        b1 = __builtin_fmaf(wb_9,  hs_9,  b1);                             \
        a1 = __builtin_fmaf(wa_10, hs_10, a1);                             \
        b1 = __builtin_fmaf(wb_10, hs_10, b1);                             \
        a1 = __builtin_fmaf(wa_11, hs_11, a1);                             \
        b1 = __builtin_fmaf(wb_11, hs_11, b1);                             \
        a1 = __builtin_fmaf(wa_12, hs_12, a1);                             \
        b1 = __builtin_fmaf(wb_12, hs_12, b1);                             \
        a1 = __builtin_fmaf(wa_13, hs_13, a1);                             \
        b1 = __builtin_fmaf(wb_13, hs_13, b1);                             \
        a2 = __builtin_fmaf(wa_14, hs_14, a2);                             \
        b2 = __builtin_fmaf(wb_14, hs_14, b2);                             \
        a2 = __builtin_fmaf(wa_15, hs_15, a2);                             \
        b2 = __builtin_fmaf(wb_15, hs_15, b2);                             \
        a2 = __builtin_fmaf(wa_16, hs_16, a2);                             \
        b2 = __builtin_fmaf(wb_16, hs_16, b2);                             \
        a2 = __builtin_fmaf(wa_17, hs_17, a2);                             \
        b2 = __builtin_fmaf(wb_17, hs_17, b2);                             \
        a2 = __builtin_fmaf(wa_18, hs_18, a2);                             \
        b2 = __builtin_fmaf(wb_18, hs_18, b2);                             \
        a2 = __builtin_fmaf(wa_19, hs_19, a2);                             \
        b2 = __builtin_fmaf(wb_19, hs_19, b2);                             \
        a2 = __builtin_fmaf(wa_20, hs_20, a2);                             \
        b2 = __builtin_fmaf(wb_20, hs_20, b2);                             \
        float accA = (a0 + a1) + a2;                                       \
        float accB = (b0 + b1) + b2;                                       \
        float vA = sigm(accA);                                             \
        float vB = __builtin_fmaf(mB, sigm(sB * accB), aB);                \
        float p   = vA * vB;                                               \
        float pSw = __shfl_xor(p, 32);                                     \
        c = __builtin_fmaf(vA, c, pSw);                                    \
        float th = tanh_stable(c);                                         \
        float h  = vB * th;                                                \
        if (hi && act) hout[(tt_) * HDIM + k] = h;                         \
        BCAST_H(h)                                                         \
    }

#define STEP4(qA_, qB_, t0_)                                               \
    STEP((qA_).x, (qB_).x, (t0_) + 0)                                      \
    STEP((qA_).y, (qB_).y, (t0_) + 1)                                      \
    STEP((qA_).z, (qB_).z, (t0_) + 2)                                      \
    STEP((qA_).w, (qB_).w, (t0_) + 3)

#define LDG4(p_) (*reinterpret_cast<const float4*>(p_))

__global__ __launch_bounds__(64, 1)
void lstm_scan_kernel(const float* __restrict__ zxA, const float* __restrict__ WhhA,
                      float* __restrict__ houtA,
                      const float* __restrict__ zxB, const float* __restrict__ WhhB,
                      float* __restrict__ houtB)
{
    const float* zxG  = (blockIdx.x == 0) ? zxA  : zxB;
    const float* Whh  = (blockIdx.x == 0) ? WhhA : WhhB;
    float*       hout = (blockIdx.x == 0) ? houtA : houtB;

    const int lane = threadIdx.x;
    const int k = lane & 31;
    const bool hi = lane >= 32;
    const bool act = k < HDIM;
    const int kk = act ? k : 0;

    const int rowA = hi ? (HDIM + kk)     : kk;              // f : i  (sigmoid)
    const int rowB = hi ? (3 * HDIM + kk) : (2 * HDIM + kk); // o : g
    const float sB = hi ? 1.0f : 2.0f;   // vB: lo tanh via 2*sigm(2x)-1, hi sigm
    const float mB = hi ? 1.0f : 2.0f;
    const float aB = hi ? 0.0f : -1.0f;

    const float* baseA = zxG + rowA * 4;   // lane's 16B slot within each group block
    const float* baseB = zxG + rowB * 4;
    const float* WA = Whh + rowA * HDIM;
    const float* WB = Whh + rowB * HDIM;

    // weights: 42 NAMED scalars -> guaranteed VGPRs
    float wa_0  = WA[0],  wa_1  = WA[1],  wa_2  = WA[2],  wa_3  = WA[3];
    float wa_4  = WA[4],  wa_5  = WA[5],  wa_6  = WA[6],  wa_7  = WA[7];
    float wa_8  = WA[8],  wa_9  = WA[9],  wa_10 = WA[10], wa_11 = WA[11];
    float wa_12 = WA[12], wa_13 = WA[13], wa_14 = WA[14], wa_15 = WA[15];
    float wa_16 = WA[16], wa_17 = WA[17], wa_18 = WA[18], wa_19 = WA[19];
    float wa_20 = WA[20];
    float wb_0  = WB[0],  wb_1  = WB[1],  wb_2  = WB[2],  wb_3  = WB[3];
    float wb_4  = WB[4],  wb_5  = WB[5],  wb_6  = WB[6],  wb_7  = WB[7];
    float wb_8  = WB[8],  wb_9  = WB[9],  wb_10 = WB[10], wb_11 = WB[11];
    float wb_12 = WB[12], wb_13 = WB[13], wb_14 = WB[14], wb_15 = WB[15];
    float wb_16 = WB[16], wb_17 = WB[17], wb_18 = WB[18], wb_19 = WB[19];
    float wb_20 = WB[20];

    // h state: 21 named scalars (wave-uniform after readlane)
    float hs_0 = 0, hs_1 = 0, hs_2 = 0, hs_3 = 0, hs_4 = 0, hs_5 = 0, hs_6 = 0;
    float hs_7 = 0, hs_8 = 0, hs_9 = 0, hs_10 = 0, hs_11 = 0, hs_12 = 0;
    float hs_13 = 0, hs_14 = 0, hs_15 = 0, hs_16 = 0, hs_17 = 0, hs_18 = 0;
    float hs_19 = 0, hs_20 = 0;
    float c = 0.0f;

    // 3-bank pipeline: bank0 = groups g..g+3, bank1 = g+4..g+7, TMP = g+8..g+11
    float4 c0A = LDG4(baseA + 0 * GSTRIDE), c0B = LDG4(baseB + 0 * GSTRIDE);
    float4 c1A = LDG4(baseA + 1 * GSTRIDE), c1B = LDG4(baseB + 1 * GSTRIDE);
    float4 c2A = LDG4(baseA + 2 * GSTRIDE), c2B = LDG4(baseB + 2 * GSTRIDE);
    float4 c3A = LDG4(baseA + 3 * GSTRIDE), c3B = LDG4(baseB + 3 * GSTRIDE);
    float4 n0A = LDG4(baseA + 4 * GSTRIDE), n0B = LDG4(baseB + 4 * GSTRIDE);
    float4 n1A = LDG4(baseA + 5 * GSTRIDE), n1B = LDG4(baseB + 5 * GSTRIDE);
    float4 n2A = LDG4(baseA + 6 * GSTRIDE), n2B = LDG4(baseB + 6 * GSTRIDE);
    float4 n3A = LDG4(baseA + 7 * GSTRIDE), n3B = LDG4(baseB + 7 * GSTRIDE);

#pragma unroll 1
    for (int g = 0; g < NGRP; g += 4) {
        // issue loads for groups g+8..g+11 (consumed 16 steps from now;
        // up to 8 groups past the end -> lands in following mapped ws)
        const float* pA = baseA + (size_t)(g + 8) * GSTRIDE;
        const float* pB = baseB + (size_t)(g + 8) * GSTRIDE;
        float4 f0A = LDG4(pA + 0 * GSTRIDE), f0B = LDG4(pB + 0 * GSTRIDE);
        float4 f1A = LDG4(pA + 1 * GSTRIDE), f1B = LDG4(pB + 1 * GSTRIDE);
        float4 f2A = LDG4(pA + 2 * GSTRIDE), f2B = LDG4(pB + 2 * GSTRIDE);
        float4 f3A = LDG4(pA + 3 * GSTRIDE), f3B = LDG4(pB + 3 * GSTRIDE);

        STEP4(c0A, c0B, (g + 0) * 4)
        STEP4(c1A, c1B, (g + 1) * 4)
        STEP4(c2A, c2B, (g + 2) * 4)
        STEP4(c3A, c3B, (g + 3) * 4)

        // rotate banks: bank0 <= bank1 (reg moves), bank1 <= TMP (vmcnt wait
        // lands here, 16 steps after issue)
        c0A = n0A; c0B = n0B; c1A = n1A; c1B = n1B;
        c2A = n2A; c2B = n2B; c3A = n3A; c3B = n3B;
        n0A = f0A; n0B = f0B; n1A = f1A; n1B = f1B;
        n2A = f2A; n2B = f2B; n3A = f3A; n3B = f3B;
    }
}

// ---------------------------------------------------------------------------
// K4: parallel zx3 from h1,h2 and folded M1,M2; GROUPED output.
// ---------------------------------------------------------------------------
__global__ void zx3_kernel(const float* __restrict__ h1, const float* __restrict__ h2,
                           const float* __restrict__ M1, const float* __restrict__ M2,
                           const float* __restrict__ b3p, float* __restrict__ zxG3)
{
    int n = blockIdx.x * blockDim.x + threadIdx.x;
    if (n >= T_LEN * GDIM) return;
    unsigned g = (unsigned)n / GSTRIDE;
    unsigned r = (unsigned)n - g * GSTRIDE;
    unsigned j = r >> 2;
    unsigned t = (g << 2) | (r & 3);
    const float* h1t = h1 + t * HDIM;
    const float* h2t = h2 + t * HDIM;
    const float* m1  = M1 + j * HDIM;
    const float* m2  = M2 + j * HDIM;
    float s = b3p[j];
#pragma unroll
    for (int kq = 0; kq < HDIM; ++kq) {
        s = __builtin_fmaf(m1[kq], h1t[kq], s);
        s = __builtin_fmaf(m2[kq], h2t[kq], s);
    }
    zxG3[n] = s;
}

// ---------------------------------------------------------------------------
// K6: final linear: out[t] = h3[t] @ W3.T + bl3   (W3: [2,21])
// ---------------------------------------------------------------------------
__global__ void out_kernel(const float* __restrict__ h3, const float* __restrict__ W3,
                           const float* __restrict__ bl3, float* __restrict__ out)
{
    int t = blockIdx.x * blockDim.x + threadIdx.x;
    if (t >= T_LEN) return;
    float s0 = bl3[0], s1 = bl3[1];
#pragma unroll
    for (int kq = 0; kq < HDIM; ++kq) {
        float h = h3[t * HDIM + kq];
        s0 = __builtin_fmaf(W3[kq], h, s0);
        s1 = __builtin_fmaf(W3[HDIM + kq], h, s1);
    }
    out[t * 2 + 0] = s0;
    out[t * 2 + 1] = s1;
}

extern "C" void kernel_launch(void* const* d_in, const int* in_sizes, int n_in,
                              void* d_out, int out_size, void* d_ws, size_t ws_size,
                              hipStream_t stream) {
    const float* src  = (const float*)d_in[0];
    const float* Wih1 = (const float*)d_in[1];
    const float* Whh1 = (const float*)d_in[2];
    const float* b1   = (const float*)d_in[3];
    const float* W1   = (const float*)d_in[4];
    const float* bl1  = (const float*)d_in[5];
    const float* Wih2 = (const float*)d_in[6];
    const float* Whh2 = (const float*)d_in[7];
    const float* b2   = (const float*)d_in[8];
    const float* W2   = (const float*)d_in[9];
    const float* bl2  = (const float*)d_in[10];
    const float* Wih3 = (const float*)d_in[11];
    const float* Whh3 = (const float*)d_in[12];
    const float* b3   = (const float*)d_in[13];
    const float* W3   = (const float*)d_in[14];
    const float* bl3  = (const float*)d_in[15];
    float* out = (float*)d_out;

    float* ws   = (float*)d_ws;
    float* zxG1 = ws;
    float* zxG2 = zxG1 + (size_t)T_LEN * GDIM;
    float* zxG3 = zxG2 + (size_t)T_LEN * GDIM;
    float* h1   = zxG3 + (size_t)T_LEN * GDIM;
    float* h2   = h1   + (size_t)T_LEN * HDIM;
    float* h3   = h2   + (size_t)T_LEN * HDIM;
    float* M1   = h3   + (size_t)T_LEN * HDIM;
    float* M2   = M1   + GDIM * HDIM;
    float* b3p  = M2   + GDIM * HDIM;

    zx12_kernel<<<(T_LEN * GDIM + 255) / 256, 256, 0, stream>>>(
        src, Wih1, b1, Wih2, b2, zxG1, zxG2);
    fold_kernel<<<(GDIM * HDIM + 255) / 256, 256, 0, stream>>>(
        Wih3, W1, bl1, W2, bl2, b3, M1, M2, b3p);
    lstm_scan_kernel<<<2, 64, 0, stream>>>(zxG1, Whh1, h1, zxG2, Whh2, h2);
    zx3_kernel<<<(T_LEN * GDIM + 255) / 256, 256, 0, stream>>>(
        h1, h2, M1, M2, b3p, zxG3);
    lstm_scan_kernel<<<1, 64, 0, stream>>>(zxG3, Whh3, h3, zxG3, Whh3, h3);
    out_kernel<<<(T_LEN + 255) / 256, 256, 0, stream>>>(h3, W3, bl3, out);
}